// Round 6
// baseline (991.377 us; speedup 1.0000x reference)
//
#include <hip/hip_runtime.h>
#include <cstdint>

#define NCLS 60
#define KC 512
#define DD 256
#define BB 32
#define NP 4096
#define CPAD 68   // cs row stride (floats): 2-way bank alias on reads = free
#define ZROW 128  // zs_d row stride (floats) = n-tile width, st64-friendly
#define LDP 260   // row stride for the sq kernels

typedef float v2f __attribute__((ext_vector_type(2)));

// Packed fp32 mul/add: lo/hi lanes are IEEE RN f32, bit-identical to scalar
// v_mul_f32/v_add_f32. asm is opaque to the compiler -> no fma contraction.
__device__ __forceinline__ v2f pk_mul(v2f a, v2f b) {
  v2f d;
  asm("v_pk_mul_f32 %0, %1, %2" : "=v"(d) : "v"(a), "v"(b));
  return d;
}
__device__ __forceinline__ v2f pk_add(v2f a, v2f b) {
  v2f d;
  asm("v_pk_add_f32 %0, %1, %2" : "=v"(d) : "v"(a), "v"(b));
  return d;
}

// Rounded fp32 multiply that cannot be fused into a following add.
__device__ __forceinline__ float mul_rn_nofuse(float a, float b) {
  float p = a * b;
  asm("" : "+v"(p));
  return p;
}

// numpy pairwise_sum of x*x over 256 contiguous floats.
__device__ __forceinline__ float np_pairwise256_sq(const float* row) {
  float h0 = 0.f, h1 = 0.f;
#pragma unroll
  for (int half = 0; half < 2; ++half) {
    const float* a = row + half * 128;
    float r[8];
#pragma unroll
    for (int j = 0; j < 8; ++j) r[j] = mul_rn_nofuse(a[j], a[j]);
    for (int blk = 1; blk < 16; ++blk) {
#pragma unroll
      for (int j = 0; j < 8; ++j) {
        float p = mul_rn_nofuse(a[blk * 8 + j], a[blk * 8 + j]);
        r[j] = r[j] + p;
      }
    }
    float res = ((r[0] + r[1]) + (r[2] + r[3])) + ((r[4] + r[5]) + (r[6] + r[7]));
    if (half == 0) h0 = res; else h1 = res;
  }
  return h0 + h1;
}

__global__ __launch_bounds__(64) void zsq_kernel(const float* __restrict__ z,
                                                 float* __restrict__ zsq) {
  __shared__ float zs[64][LDP];
  int t = threadIdx.x;
  int b = blockIdx.x >> 6;
  int n0 = (blockIdx.x & 63) * 64;
  const float* zb = z + (size_t)b * DD * NP;
  for (int d = 0; d < DD; ++d) zs[t][d] = zb[(size_t)d * NP + n0 + t];
  __syncthreads();
  zsq[b * NP + n0 + t] = np_pairwise256_sq(&zs[t][0]);
}

__global__ __launch_bounds__(64) void cbsq_kernel(const float* __restrict__ emb,
                                                  float* __restrict__ cbsq) {
  __shared__ float cs[64][LDP];
  int t = threadIdx.x;
  int r0 = blockIdx.x * 64;
  const float4* e4 = (const float4*)emb;
  for (int rr = 0; rr < 64; ++rr) {
    float4 v = e4[(size_t)(r0 + rr) * 64 + t];
    *(float4*)&cs[rr][t * 4] = v;
  }
  __syncthreads();
  cbsq[r0 + t] = np_pairwise256_sq(&cs[t][0]);
}

// ---- main: 8x4 micro-tile, packed-fp32, np-einsum SSE chain order ----
// Z kept in native [d][n] layout in LDS (no transpose anywhere):
//   z-pair (z[d][n], z[d+1][n]) = 2 scalar LDS reads 512B apart -> ds_read2st64.
// C kept [k][d] (straight copy), rows padded to 68 (2-way alias = free).
// block 256 thr: tn=t>>4 owns n-rows {tn+16i,i<8}; tk=t&15 owns k {tk+16j,j<4}.
__global__ __launch_bounds__(256, 2) void vq_main_kernel(
    const float* __restrict__ z, const int* __restrict__ c,
    const float* __restrict__ emb, const float* __restrict__ zsq,
    const float* __restrict__ cbsq, int* __restrict__ idx_out) {
  __shared__ __align__(16) float zs_d[64][ZROW];  // [d_local][n] — 32 KB
  __shared__ __align__(16) float cs[64][CPAD];    // [k_local][d_local] — 17 KB
  const int t = threadIdx.x;
  const int b = blockIdx.y;
  const int n0 = blockIdx.x * 128;
  const int tn = t >> 4, tk = t & 15;
  const int cls = c[b];
  const float* __restrict__ zb = z + (size_t)b * DD * NP;
  const float* __restrict__ cb = emb + (size_t)cls * KC * DD;
  const float* __restrict__ cbsqb = cbsq + cls * KC;

  float zsqv[8];
#pragma unroll
  for (int i = 0; i < 8; ++i) zsqv[i] = zsq[b * NP + n0 + tn + 16 * i];

  float m[8];
  int bi[8];
#pragma unroll
  for (int i = 0; i < 8; ++i) { m[i] = 3.4e38f; bi[i] = 0; }

#pragma unroll 1
  for (int kt = 0; kt < 8; ++kt) {
    const float* __restrict__ cbk = cb + (size_t)kt * 64 * DD;
    v2f A[8][4][2];
#pragma unroll
    for (int i = 0; i < 8; ++i)
#pragma unroll
      for (int j = 0; j < 4; ++j) {
        A[i][j][0] = (v2f){0.f, 0.f};
        A[i][j][1] = (v2f){0.f, 0.f};
      }

#pragma unroll 1
    for (int dc = 0; dc < 4; ++dc) {
      const int d0g = dc * 64;
      __syncthreads();  // previous chunk fully consumed
      // stage z chunk [64 d][128 n], native layout: b128 in, b128 out.
      // wave phase (8 lanes, same d, n4 consecutive) -> banks 4*n4+l: conflict-free.
#pragma unroll
      for (int it = 0; it < 8; ++it) {
        int flat = it * 256 + t;
        int d = flat >> 5, n4 = flat & 31;
        *(float4*)&zs_d[d][n4 * 4] =
            *(const float4*)&zb[(size_t)(d0g + d) * NP + n0 + n4 * 4];
      }
      // stage cb chunk [64 k][64 d]: straight copy, conflict-free.
#pragma unroll
      for (int it = 0; it < 4; ++it) {
        int flat = it * 256 + t;
        int kr = flat >> 4, dq = flat & 15;
        *(float4*)&cs[kr][dq * 4] =
            *(const float4*)&cbk[(size_t)kr * DD + d0g + dq * 4];
      }
      __syncthreads();

#pragma unroll 1
      for (int t16 = 0; t16 < 4; ++t16) {
#pragma unroll
        for (int s = 3; s >= 0; --s) {
          const int d0 = t16 * 16 + s * 4;
          // c-operand pairs for the 4 k's (b64 reads, 2-way alias = free)
          v2f cp0[4], cp1[4];
#pragma unroll
          for (int j = 0; j < 4; ++j) {
            cp0[j] = *(const v2f*)&cs[tk + 16 * j][d0];
            cp1[j] = *(const v2f*)&cs[tk + 16 * j][d0 + 2];
          }
#pragma unroll
          for (int i = 0; i < 8; ++i) {
            const int ni = tn + 16 * i;
            // (z[d0][ni], z[d0+1][ni]) -> ds_read2st64 pair; broadcast across tk
            v2f zp0 = {zs_d[d0][ni], zs_d[d0 + 1][ni]};
            v2f zp1 = {zs_d[d0 + 2][ni], zs_d[d0 + 3][ni]};
#pragma unroll
            for (int j = 0; j < 4; ++j) {
              A[i][j][0] = pk_add(pk_mul(zp0, cp0[j]), A[i][j][0]);
              A[i][j][1] = pk_add(pk_mul(zp1, cp1[j]), A[i][j][1]);
            }
          }
        }
      }
    }

    // npyv hadd + dist + first-min update (k strictly ascending per thread)
#pragma unroll
    for (int j = 0; j < 4; ++j) {
      const int k = kt * 64 + tk + 16 * j;
      const float cq = cbsqb[k];
#pragma unroll
      for (int i = 0; i < 8; ++i) {
        float dot = (A[i][j][0].x + A[i][j][0].y) + (A[i][j][1].x + A[i][j][1].y);
        float dist = (zsqv[i] - 2.0f * dot) + cq;  // 2*dot exact (pow2 mul)
        if (dist < m[i]) { m[i] = dist; bi[i] = k; }
      }
    }
  }

  // lex-min (value, index) across the 16 tk-lanes sharing each n
#pragma unroll
  for (int i = 0; i < 8; ++i) {
#pragma unroll
    for (int off = 8; off >= 1; off >>= 1) {
      float om = __shfl_xor(m[i], off);
      int oi = __shfl_xor(bi[i], off);
      if (om < m[i] || (om == m[i] && oi < bi[i])) { m[i] = om; bi[i] = oi; }
    }
  }
  if (tk == 0) {
#pragma unroll
    for (int i = 0; i < 8; ++i) idx_out[b * NP + n0 + tn + 16 * i] = bi[i];
  }
}

// ---- gather selected rows -> [B,H,W,D] (bitwise copy of embedding rows) ----
__global__ __launch_bounds__(256) void vq_gather_kernel(
    const int* __restrict__ c, const float* __restrict__ emb,
    const int* __restrict__ idx, float* __restrict__ out) {
  int t = threadIdx.x;
  int r = blockIdx.x * 4 + (t >> 6);
  int lane = t & 63;
  int b = r >> 12;
  int k = idx[r];
  const float4* src = (const float4*)(emb + (size_t)(c[b] * KC + k) * DD);
  float4* dst = (float4*)(out + (size_t)r * DD);
  dst[lane] = src[lane];
}

extern "C" void kernel_launch(void* const* d_in, const int* in_sizes, int n_in,
                              void* d_out, int out_size, void* d_ws, size_t ws_size,
                              hipStream_t stream) {
  const float* z = (const float*)d_in[0];    // [32,256,64,64]
  const int* c = (const int*)d_in[1];        // [32]
  const float* emb = (const float*)d_in[2];  // [30720,256]
  float* out = (float*)d_out;                // [32,64,64,256]

  char* ws = (char*)d_ws;
  float* zsq = (float*)ws;                       // 131072 f32
  float* cbsq = (float*)(ws + 524288);           // 30720 f32
  int* idx = (int*)(ws + 524288 + 122880);       // 131072 i32

  zsq_kernel<<<BB * (NP / 64), 64, 0, stream>>>(z, zsq);
  cbsq_kernel<<<(NCLS * KC) / 64, 64, 0, stream>>>(emb, cbsq);
  dim3 gA(NP / 128, BB);
  vq_main_kernel<<<gA, 256, 0, stream>>>(z, c, emb, zsq, cbsq, idx);
  vq_gather_kernel<<<(BB * NP) / 4, 256, 0, stream>>>(c, emb, idx, out);
}